// Round 8
// baseline (2495.012 us; speedup 1.0000x reference)
//
#include <hip/hip_runtime.h>
#include <hip/hip_bf16.h>
#include <hip/hip_cooperative_groups.h>

// Problem constants
constexpr int B_ = 256;
constexpr int N_ = 128;
constexpr int E_ = 256;
constexpr int H_ = 512;
constexpr int T_ = 129;          // N+1
constexpr float NEGV = -1e30f;

typedef __attribute__((ext_vector_type(8))) short bf16x8;
typedef __attribute__((ext_vector_type(4))) float f32x4;

__device__ __forceinline__ float sigm(float x) { return 1.0f / (1.0f + __expf(-x)); }

// f32 -> bf16 bits, round-to-nearest-even
__device__ __forceinline__ short f2bf(float f) {
    union { float f; unsigned int u; } v; v.f = f;
    unsigned int r = (v.u + 0x7FFFu + ((v.u >> 16) & 1u)) >> 16;
    return (short)r;
}

// ---------------------------------------------------------------------------
// node_embeds[b,n,e] = sum_d adj[b,n,d] * Wemb[e,d] + bemb[e]  -> bf16
__global__ __launch_bounds__(256)
void k_embed(const float* __restrict__ adj, const float* __restrict__ Wemb,
             const float* __restrict__ bemb, ushort* __restrict__ ne) {
    __shared__ float Wl[32][E_];
    __shared__ float As[16][33];
    const int row0 = blockIdx.x * 16;
    const int tid = threadIdx.x;
    float acc[16];
#pragma unroll
    for (int r = 0; r < 16; ++r) acc[r] = 0.f;

    for (int k0 = 0; k0 < N_; k0 += 32) {
        for (int idx = tid; idx < 32 * E_; idx += 256) {
            int kk = idx >> 8, e = idx & 255;
            Wl[kk][e] = Wemb[e * N_ + k0 + kk];
        }
        for (int idx = tid; idx < 16 * 32; idx += 256) {
            int r = idx >> 5, kk = idx & 31;
            As[r][kk] = adj[(size_t)(row0 + r) * N_ + k0 + kk];
        }
        __syncthreads();
#pragma unroll 8
        for (int kk = 0; kk < 32; ++kk) {
            float w = Wl[kk][tid];
#pragma unroll
            for (int r = 0; r < 16; ++r) acc[r] += As[r][kk] * w;
        }
        __syncthreads();
    }
    float be = bemb[tid];
#pragma unroll
    for (int r = 0; r < 16; ++r)
        ne[(size_t)(row0 + r) * E_ + tid] = (ushort)f2bf(acc[r] + be);
}

// ---------------------------------------------------------------------------
// init: zero h0/loss/flags, build pos table, fill EOS slot of ext (bf16)
__global__ void k_init(const int* __restrict__ tgt, const float* __restrict__ eos,
                       ushort* __restrict__ hbuf0, float* __restrict__ loss,
                       int* __restrict__ pos, ushort* __restrict__ ext,
                       unsigned int* __restrict__ flags) {
    int idx = blockIdx.x * blockDim.x + threadIdx.x;   // grid covers B*H = 131072
    if (idx < B_ * H_) hbuf0[idx] = 0;
    if (idx == 0) loss[0] = 0.f;
    if (idx < 256) flags[idx] = 0;                     // step flags (re-poisoned each call)
    if (idx < B_ * T_) {
        int b = idx / T_, t = idx % T_;
        pos[b * T_ + tgt[b * T_ + t]] = t;
    }
    if (idx < B_ * H_) {
        int b = idx / H_, u = idx % H_;
        ext[((size_t)b * T_ + N_) * H_ + u] = (ushort)f2bf(eos[u]);
    }
}

// ---------------------------------------------------------------------------
// decoder teacher-forced inputs (bf16)
__global__ __launch_bounds__(256)
void k_decx(const int* __restrict__ tgt, const ushort* __restrict__ ne,
            const float* __restrict__ dstart, ushort* __restrict__ dx) {
    int bt = blockIdx.x;            // b*T + t
    int b = bt / T_, t = bt % T_;
    int e = threadIdx.x;
    ushort v;
    if (t == 0) v = (ushort)f2bf(dstart[e]);
    else {
        int tg = tgt[b * T_ + t - 1];
        v = (tg >= N_) ? (ushort)0 : ne[((size_t)b * N_ + tg) * E_ + e];
    }
    dx[(size_t)bt * E_ + e] = v;
}

// ---------------------------------------------------------------------------
// Weight pre-pack: both phases -> bf16 fragments in the exact per-thread order
// the recurrence consumes: wpack[phase][ut][wave][kc][lane] (16B frags).
__global__ __launch_bounds__(256)
void k_wprep(const float* __restrict__ eWih, const float* __restrict__ eWhh,
             const float* __restrict__ dWih, const float* __restrict__ dWhh,
             ushort* __restrict__ wpack) {
    int gid = blockIdx.x * 256 + threadIdx.x;      // total 2*32*4*24*64 = 393216
    int lane = gid & 63;
    int rem = gid >> 6;
    int kc = rem % 24;  rem /= 24;
    int wave = rem & 3; rem >>= 2;
    int ut = rem & 31;  rem >>= 5;
    int phase = rem;                                // 0=enc, 1=dec
    if (phase > 1) return;

    const float* Wih = phase ? dWih : eWih;
    const float* Whh = phase ? dWhh : eWhh;
    const int l15 = lane & 15, l4 = lane >> 4;
    const int grow = wave * H_ + ut * 16 + l15;     // gate row in [4H]
    const float* src = (kc < 8) ? (Wih + (size_t)grow * E_ + kc * 32 + l4 * 8)
                                : (Whh + (size_t)grow * H_ + (kc - 8) * 32 + l4 * 8);
    float4 v0 = reinterpret_cast<const float4*>(src)[0];
    float4 v1 = reinterpret_cast<const float4*>(src)[1];
    ushort f[8];
    f[0] = (ushort)f2bf(v0.x); f[1] = (ushort)f2bf(v0.y);
    f[2] = (ushort)f2bf(v0.z); f[3] = (ushort)f2bf(v0.w);
    f[4] = (ushort)f2bf(v1.x); f[5] = (ushort)f2bf(v1.y);
    f[6] = (ushort)f2bf(v1.z); f[7] = (ushort)f2bf(v1.w);
    *reinterpret_cast<uint4*>(wpack + (size_t)gid * 8) = *reinterpret_cast<uint4*>(f);
}

// ---------------------------------------------------------------------------
// Persistent cooperative recurrence, bt-group-scoped sync (NO grid.sync fence).
//
// Grid: 256 wgs = 8 bt-groups(32 batch rows) x 32 ut(16 units). bt = bid&7 so a
// group's 32 wgs land on one XCD under the round-robin mapping (perf hint ONLY).
// Sync protocol (correct on ANY XCD mapping):
//   - ALL h-exchange data (h dbuf) and step flags use agent-scope relaxed
//     atomics -> sc1, L2-bypassing, coherent at L3. Nothing coherence-critical
//     ever sits in an XCD-private L2, so no wbl2/inv fences are needed.
//   - Writer order: h sc1-stores -> __syncthreads (compiler drains vmcnt(0)
//     before s_barrier) -> tid0 relaxed sc1 flag store (value t+1, monotonic,
//     no reset -> no ABA). Flag reaches L3 strictly after h data.
//   - Reader order: poll flags >= t (wave0) -> __syncthreads -> sc1 h loads.
//   - Double buffer safe: a wg's flag(t)=t+1 implies its reads of h_{t-1}
//     finished, so overwriting hb[(t+1)&1] at step t+1 cannot race.
//   - Deadlock-free: cooperative launch guarantees co-residency; flags monotonic.
// Weights (24 frags = 96 VGPR) + c-state persist in registers for all 257 steps.
__global__ __launch_bounds__(256, 1)
void k_recur2(const ushort* __restrict__ ne, const ushort* __restrict__ dx,
              const ushort* __restrict__ wpackE, const ushort* __restrict__ wpackD,
              const float* __restrict__ ebih, const float* __restrict__ ebhh,
              const float* __restrict__ dbih, const float* __restrict__ dbhh,
              ushort* __restrict__ hb0, ushort* __restrict__ hb1,
              ushort* __restrict__ ext, ushort* __restrict__ hdec,
              unsigned int* __restrict__ flags) {
    __shared__ ushort Alds[96 * 32 * 8];           // 48KB A-tile
    __shared__ float zlds[4][2][16][17];
    __shared__ float blds[64];

    const int bid = blockIdx.x;
    const int bt = bid & 7, ut = bid >> 3;
    const int b0 = bt * 32, u0 = ut * 16;
    const int tid = threadIdx.x;
    const int wave = tid >> 6, lane = tid & 63;
    const int l15 = lane & 15, l4 = lane >> 4;
    const int cj = tid & 15, cr = tid >> 4;

    unsigned int* flg = flags + bt * 32;           // my group's 32 flags

    bf16x8 w[24];
    {
        const ushort* wp = wpackE + ((size_t)(ut * 4 + wave) * 24 * 64) * 8;
#pragma unroll
        for (int kc = 0; kc < 24; ++kc)
            w[kc] = *reinterpret_cast<const bf16x8*>(wp + ((size_t)kc * 64 + lane) * 8);
        if (tid < 64)
            blds[tid] = ebih[(tid >> 4) * H_ + u0 + (tid & 15)]
                      + ebhh[(tid >> 4) * H_ + u0 + (tid & 15)];
    }
    float creg0 = 0.f, creg1 = 0.f;                // persistent cell state

    for (int t = 0; t < N_ + T_; ++t) {
        const bool enc = (t < N_);
        const int tt = enc ? t : (t - N_);
        const ushort* hc = (t & 1) ? hb1 : hb0;
        ushort* hn = (t & 1) ? hb0 : hb1;

        // ---- x-part staging first (read-only data, normal/L2 path; overlaps poll)
        const ushort* xb = enc ? (ne + (size_t)tt * E_) : (dx + (size_t)tt * E_);
        const int xstr = enc ? (N_ * E_) : (T_ * E_);
#pragma unroll
        for (int i = 0; i < 4; ++i) {
            int slot = i * 256 + tid;
            int kcs = slot >> 5, row = slot & 31;
            uint4 v = *reinterpret_cast<const uint4*>(xb + (size_t)(b0 + row) * xstr + kcs * 8);
            *reinterpret_cast<uint4*>(&Alds[slot * 8]) = v;
        }

        // ---- wait for h_{t-1} from all 32 wgs of my bt-group
        if (t > 0 && wave == 0) {
            const unsigned int tv = (unsigned int)t;
            const int fi = lane & 31;
            while (true) {
                unsigned int v = __hip_atomic_load(&flg[fi], __ATOMIC_RELAXED,
                                                   __HIP_MEMORY_SCOPE_AGENT);
                if (__all((int)(v >= tv))) break;
                __builtin_amdgcn_s_sleep(2);
            }
        }
        __syncthreads();

        // ---- h-part staging via sc1 loads (L3-coherent)
#pragma unroll
        for (int i = 4; i < 12; ++i) {
            int slot = i * 256 + tid;
            int kcs = slot >> 5, row = slot & 31;
            const unsigned int* src = reinterpret_cast<const unsigned int*>(
                hc + (size_t)(b0 + row) * H_ + (kcs - 32) * 8);
            unsigned int v0 = __hip_atomic_load(&src[0], __ATOMIC_RELAXED, __HIP_MEMORY_SCOPE_AGENT);
            unsigned int v1 = __hip_atomic_load(&src[1], __ATOMIC_RELAXED, __HIP_MEMORY_SCOPE_AGENT);
            unsigned int v2 = __hip_atomic_load(&src[2], __ATOMIC_RELAXED, __HIP_MEMORY_SCOPE_AGENT);
            unsigned int v3 = __hip_atomic_load(&src[3], __ATOMIC_RELAXED, __HIP_MEMORY_SCOPE_AGENT);
            uint4 v; v.x = v0; v.y = v1; v.z = v2; v.w = v3;
            *reinterpret_cast<uint4*>(&Alds[slot * 8]) = v;
        }
        __syncthreads();

        // ---- MFMA: z[32 x 16cols] for this wave's gate
        f32x4 acc0 = {0.f, 0.f, 0.f, 0.f};
        f32x4 acc1 = {0.f, 0.f, 0.f, 0.f};
#pragma unroll
        for (int kc = 0; kc < 24; ++kc) {
            const int sbase = (kc * 4 + l4) * 32;
            bf16x8 a0 = *reinterpret_cast<const bf16x8*>(&Alds[(sbase + l15) * 8]);
            bf16x8 a1 = *reinterpret_cast<const bf16x8*>(&Alds[(sbase + 16 + l15) * 8]);
            acc0 = __builtin_amdgcn_mfma_f32_16x16x32_bf16(a0, w[kc], acc0, 0, 0, 0);
            acc1 = __builtin_amdgcn_mfma_f32_16x16x32_bf16(a1, w[kc], acc1, 0, 0, 0);
        }
        // C/D layout: col = lane&15, row = (lane>>4)*4 + reg  [m89-verified]
#pragma unroll
        for (int q = 0; q < 4; ++q) {
            zlds[wave][0][l4 * 4 + q][l15] = acc0[q];
            zlds[wave][1][l4 * 4 + q][l15] = acc1[q];
        }
        __syncthreads();

        // ---- cell update (c in registers), save h to ext/hdec (normal stores)
        ushort* sv = enc ? ext : hdec;
        ushort hbits[2];
#pragma unroll
        for (int rr = 0; rr < 2; ++rr) {
            const int row = b0 + cr + rr * 16;
            float zi = zlds[0][rr][cr][cj] + blds[cj];
            float zf = zlds[1][rr][cr][cj] + blds[16 + cj];
            float zg = zlds[2][rr][cr][cj] + blds[32 + cj];
            float zo = zlds[3][rr][cr][cj] + blds[48 + cj];
            float cold = rr ? creg1 : creg0;
            float cn = sigm(zf) * cold + sigm(zi) * tanhf(zg);
            float hv = sigm(zo) * tanhf(cn);
            if (rr) creg1 = cn; else creg0 = cn;
            hbits[rr] = (ushort)f2bf(hv);
            sv[((size_t)row * T_ + tt) * H_ + u0 + cj] = hbits[rr];
        }
        // ---- publish h_t via sc1 stores (pack 2 units/uint; even lanes store)
#pragma unroll
        for (int rr = 0; rr < 2; ++rr) {
            const int row = b0 + cr + rr * 16;
            int other = __shfl_xor((int)hbits[rr], 1);
            if ((lane & 1) == 0) {
                unsigned int hp = ((unsigned int)hbits[rr] & 0xFFFFu)
                                | (((unsigned int)other & 0xFFFFu) << 16);
                unsigned int* dstp = reinterpret_cast<unsigned int*>(
                    hn + (size_t)row * H_ + u0 + cj);
                __hip_atomic_store(dstp, hp, __ATOMIC_RELAXED, __HIP_MEMORY_SCOPE_AGENT);
            }
        }
        __syncthreads();   // drains all threads' sc1 stores to L3 before the flag
        if (tid == 0)
            __hip_atomic_store(&flg[ut], (unsigned int)(t + 1), __ATOMIC_RELAXED,
                               __HIP_MEMORY_SCOPE_AGENT);

        // ---- phase switch: reload decoder weights/bias (blds next read is 2
        //      barriers away in iteration N_, so the wave0 write is race-free)
        if (t == N_ - 1) {
            const ushort* wp = wpackD + ((size_t)(ut * 4 + wave) * 24 * 64) * 8;
#pragma unroll
            for (int kc = 0; kc < 24; ++kc)
                w[kc] = *reinterpret_cast<const bf16x8*>(wp + ((size_t)kc * 64 + lane) * 8);
            if (tid < 64)
                blds[tid] = dbih[(tid >> 4) * H_ + u0 + (tid & 15)]
                          + dbhh[(tid >> 4) * H_ + u0 + (tid & 15)];
        }
    }
}

// ---------------------------------------------------------------------------
// Batched attention + masked log-softmax + CE (unchanged from passing version)
constexpr int TT = 16;
__global__ __launch_bounds__(512)
void k_attn(const __hip_bfloat16* __restrict__ ext,
            const __hip_bfloat16* __restrict__ hdec,
            const int* __restrict__ pos, const int* __restrict__ tgt,
            float* __restrict__ loss) {
    __shared__ float ht[TT][H_];
    __shared__ float key[H_];
    __shared__ float lg[TT][T_ + 3];
    __shared__ float bl[TT];
    const int b = blockIdx.x / 9;
    const int t0 = (blockIdx.x % 9) * TT;
    const int tid = threadIdx.x;
    const int g = tid >> 5, l = tid & 31;

    for (int idx = tid; idx < TT * H_; idx += 512) {
        int tl = idx >> 9, u = idx & 511;
        int t = t0 + tl;
        ht[tl][u] = (t < T_) ? __bfloat162float(hdec[((size_t)b * T_ + t) * H_ + u]) : 0.f;
    }
    __syncthreads();

    for (int j = 0; j < T_; ++j) {
        key[tid] = __bfloat162float(ext[((size_t)b * T_ + j) * H_ + tid]);
        __syncthreads();
        float s = 0.f;
#pragma unroll
        for (int q = 0; q < H_ / 32; ++q) s += ht[g][l + q * 32] * key[l + q * 32];
        s += __shfl_xor(s, 16); s += __shfl_xor(s, 8); s += __shfl_xor(s, 4);
        s += __shfl_xor(s, 2);  s += __shfl_xor(s, 1);
        if (l == 0) {
            int t = t0 + g;
            lg[g][j] = (t < T_ && pos[b * T_ + j] < t) ? NEGV : s;
        }
        __syncthreads();
    }

    const int t = t0 + g;
    float mx = -3.4e38f;
    for (int j = l; j < T_; j += 32) mx = fmaxf(mx, lg[g][j]);
    mx = fmaxf(mx, __shfl_xor(mx, 16)); mx = fmaxf(mx, __shfl_xor(mx, 8));
    mx = fmaxf(mx, __shfl_xor(mx, 4));  mx = fmaxf(mx, __shfl_xor(mx, 2));
    mx = fmaxf(mx, __shfl_xor(mx, 1));
    float se = 0.f;
    for (int j = l; j < T_; j += 32) se += __expf(lg[g][j] - mx);
    se += __shfl_xor(se, 16); se += __shfl_xor(se, 8); se += __shfl_xor(se, 4);
    se += __shfl_xor(se, 2);  se += __shfl_xor(se, 1);
    float lval = 0.f;
    if (l == 0 && t < T_) {
        int tg = tgt[b * T_ + t];
        lval = mx + __logf(se) - lg[g][tg];
    }
    if (l == 0) bl[g] = (t < T_) ? lval : 0.f;
    __syncthreads();
    if (tid == 0) {
        float s = 0.f;
#pragma unroll
        for (int q = 0; q < TT; ++q) s += bl[q];
        atomicAdd(loss, s);
    }
}

__global__ void k_final(const float* __restrict__ loss, float* __restrict__ out) {
    out[0] = loss[0] / (float)(B_ * T_);
}

// ---------------------------------------------------------------------------
extern "C" void kernel_launch(void* const* d_in, const int* in_sizes, int n_in,
                              void* d_out, int out_size, void* d_ws, size_t ws_size,
                              hipStream_t stream) {
    const float* adj    = (const float*)d_in[0];
    const int*   tgt    = (const int*)d_in[1];
    const float* Wemb   = (const float*)d_in[2];
    const float* bemb   = (const float*)d_in[3];
    const float* eWih   = (const float*)d_in[4];
    const float* eWhh   = (const float*)d_in[5];
    const float* ebih   = (const float*)d_in[6];
    const float* ebhh   = (const float*)d_in[7];
    const float* dWih   = (const float*)d_in[8];
    const float* dWhh   = (const float*)d_in[9];
    const float* dbih   = (const float*)d_in[10];
    const float* dbhh   = (const float*)d_in[11];
    const float* dstart = (const float*)d_in[12];
    const float* eos    = (const float*)d_in[13];

    // workspace layout (bf16 activations)
    char* wsb = (char*)d_ws;
    ushort* ne    = (ushort*)wsb;  wsb += (size_t)B_ * N_ * E_ * 2;        // 16.8MB
    ushort* dxp   = (ushort*)wsb;  wsb += (size_t)B_ * T_ * E_ * 2;        // 16.9MB
    ushort* hb0   = (ushort*)wsb;  wsb += (size_t)B_ * H_ * 2;
    ushort* hb1   = (ushort*)wsb;  wsb += (size_t)B_ * H_ * 2;
    ushort* ext   = (ushort*)wsb;  wsb += (size_t)B_ * T_ * H_ * 2;        // 33.8MB
    ushort* hdec  = (ushort*)wsb;  wsb += (size_t)B_ * T_ * H_ * 2;        // 33.8MB
    ushort* wpack = (ushort*)wsb;  wsb += (size_t)2 * 32 * 4 * 24 * 64 * 8 * 2; // 6.3MB
    int*    pos   = (int*)wsb;     wsb += (size_t)B_ * T_ * 4;
    unsigned int* flags = (unsigned int*)wsb; wsb += 256 * 4;
    float*  lacc  = (float*)wsb;

    ushort* wpackE = wpack;
    ushort* wpackD = wpack + (size_t)32 * 4 * 24 * 64 * 8;

    k_embed<<<(B_ * N_) / 16, 256, 0, stream>>>(adj, Wemb, bemb, ne);
    k_init<<<(B_ * H_) / 256, 256, 0, stream>>>(tgt, eos, hb0, lacc, pos, ext, flags);
    k_decx<<<B_ * T_, 256, 0, stream>>>(tgt, ne, dstart, dxp);
    k_wprep<<<1536, 256, 0, stream>>>(eWih, eWhh, dWih, dWhh, wpack);

    // persistent cooperative recurrence with bt-group flag sync
    {
        const ushort* a_ne = ne; const ushort* a_dx = dxp;
        const ushort* a_wpE = wpackE; const ushort* a_wpD = wpackD;
        ushort* a_hb0 = hb0; ushort* a_hb1 = hb1;
        ushort* a_ext = ext; ushort* a_hdec = hdec;
        unsigned int* a_flags = flags;
        void* args[] = {
            (void*)&a_ne, (void*)&a_dx, (void*)&a_wpE, (void*)&a_wpD,
            (void*)&ebih, (void*)&ebhh, (void*)&dbih, (void*)&dbhh,
            (void*)&a_hb0, (void*)&a_hb1, (void*)&a_ext, (void*)&a_hdec,
            (void*)&a_flags
        };
        hipLaunchCooperativeKernel(reinterpret_cast<const void*>(&k_recur2),
                                   dim3(256), dim3(256), args, 0, stream);
    }

    k_attn<<<B_ * 9, 512, 0, stream>>>((const __hip_bfloat16*)ext,
                                       (const __hip_bfloat16*)hdec, pos, tgt, lacc);
    k_final<<<1, 1, 0, stream>>>(lacc, (float*)d_out);
}